// Round 1
// baseline (2635.358 us; speedup 1.0000x reference)
//
#include <hip/hip_runtime.h>
#include <cmath>

#define LK   50      // look_back
#define NOUT 3
#define FF   64      // feature_num
#define BB   2048    // batch
#define HH   128     // units
#define BT   8       // batch rows per workgroup
#define NWG  (BB/BT) // 256 workgroups
#define NTHR 256

// encoder outputs [B][L][H] — device global to avoid ws_size dependency (52.4 MB BSS)
__device__ float g_enc[(size_t)BB * LK * HH];

__device__ __forceinline__ float sigf(float x) { return 1.0f / (1.0f + __expf(-x)); }
__device__ __forceinline__ float tanhff(float x) {
    // tanh(x) = 1 - 2/(e^{2x}+1); saturates correctly at +-1
    return 1.0f - 2.0f / (__expf(2.0f * x) + 1.0f);
}

__global__ __launch_bounds__(NTHR)
void darnn_kernel(const float* __restrict__ x,
                  const float* __restrict__ eWih, const float* __restrict__ eWhh,
                  const float* __restrict__ ebih, const float* __restrict__ ebhh,
                  const float* __restrict__ aw,   const float* __restrict__ ab,
                  const float* __restrict__ dWih, const float* __restrict__ dWhh,
                  const float* __restrict__ dbih, const float* __restrict__ dbhh,
                  const float* __restrict__ ddw,  const float* __restrict__ ddb,
                  const float* __restrict__ dlw,  const float* __restrict__ dlb,
                  const float* __restrict__ fcw,  const float* __restrict__ fcb,
                  const float* __restrict__ ow,   const float* __restrict__ ob,
                  float* __restrict__ out)
{
    __shared__ float s_h[BT][HH];       // hidden state (enc, then dec)
    __shared__ float s_c[BT][HH];       // cell state
    __shared__ float s_xt[BT][FF];      // x tile for step t
    __shared__ float s_eb[BT][FF];      // attn scores e -> xin
    __shared__ float s_g[512 * 9];      // gate pre-activations, pitch 9 (bank-conflict-free)
    __shared__ float s_hp[BT][HH];      // decoder hpart
    __shared__ float s_part[4][BT * LK];// per-wave score partials
    __shared__ float s_alpha[BT][LK];   // temporal attention weights
    __shared__ float s_ctx[BT][HH];     // context vector
    __shared__ float s_y1[BT][FF];      // head intermediate

    const int tid = threadIdx.x;
    const int b0  = blockIdx.x * BT;

    // init encoder h, c = 0
    for (int i = tid; i < BT * HH; i += NTHR) { (&s_h[0][0])[i] = 0.0f; (&s_c[0][0])[i] = 0.0f; }
    __syncthreads();

    // ================= ENCODER: 50 steps =================
#pragma unroll 1
    for (int t = 0; t < LK; ++t) {
        // stage x_t tile
        for (int i = tid; i < BT * FF; i += NTHR) {
            int r = i >> 6, f = i & 63;
            s_xt[r][f] = x[((b0 + r) * LK + t) * FF + f];
        }
        __syncthreads();

        // input attention: e[r][col] = tanh(b + [xt,h] . w_t[:,col]); one wave per row-pair
        {
            const int col = tid & 63, rg = tid >> 6;
            const int r0 = rg * 2;
            float a0 = ab[t * FF + col], a1 = a0;
            const float* w = aw + (size_t)t * 192 * 64 + col;
#pragma unroll 4
            for (int k = 0; k < FF; ++k) {
                float wv = w[k * 64];
                a0 += s_xt[r0][k] * wv; a1 += s_xt[r0 + 1][k] * wv;
            }
#pragma unroll 4
            for (int k = 0; k < HH; ++k) {
                float wv = w[(64 + k) * 64];
                a0 += s_h[r0][k] * wv; a1 += s_h[r0 + 1][k] * wv;
            }
            s_eb[r0][col]     = tanhff(a0);
            s_eb[r0 + 1][col] = tanhff(a1);
        }
        __syncthreads();

        // softmax over 64 features per row, xin = softmax(e) * xt   (8 serial threads)
        if (tid < BT) {
            const int r = tid;
            float mx = -1e30f;
            for (int k = 0; k < FF; ++k) mx = fmaxf(mx, s_eb[r][k]);
            float sm = 0.0f;
            for (int k = 0; k < FF; ++k) { float e = __expf(s_eb[r][k] - mx); sm += e; s_eb[r][k] = e; }
            float inv = 1.0f / sm;
            for (int k = 0; k < FF; ++k) s_eb[r][k] = s_eb[r][k] * inv * s_xt[r][k];
        }
        __syncthreads();

        // LSTM gates: thread owns gates j=tid and j=tid+256; acc over 8 rows
        {
            const int j1 = tid, j2 = tid + 256;
            float acc1[BT], acc2[BT];
            const float bb1 = ebih[j1] + ebhh[j1];
            const float bb2 = ebih[j2] + ebhh[j2];
#pragma unroll
            for (int r = 0; r < BT; ++r) { acc1[r] = bb1; acc2[r] = bb2; }
            const float4* w1p = (const float4*)(eWih + j1 * FF);
            const float4* w2p = (const float4*)(eWih + j2 * FF);
#pragma unroll 4
            for (int kc = 0; kc < FF / 4; ++kc) {
                float4 w1 = w1p[kc], w2 = w2p[kc];
#pragma unroll
                for (int r = 0; r < BT; ++r) {
                    float4 xv = *(const float4*)&s_eb[r][kc * 4];
                    acc1[r] += xv.x*w1.x + xv.y*w1.y + xv.z*w1.z + xv.w*w1.w;
                    acc2[r] += xv.x*w2.x + xv.y*w2.y + xv.z*w2.z + xv.w*w2.w;
                }
            }
            const float4* u1p = (const float4*)(eWhh + j1 * HH);
            const float4* u2p = (const float4*)(eWhh + j2 * HH);
#pragma unroll 4
            for (int kc = 0; kc < HH / 4; ++kc) {
                float4 w1 = u1p[kc], w2 = u2p[kc];
#pragma unroll
                for (int r = 0; r < BT; ++r) {
                    float4 hv = *(const float4*)&s_h[r][kc * 4];
                    acc1[r] += hv.x*w1.x + hv.y*w1.y + hv.z*w1.z + hv.w*w1.w;
                    acc2[r] += hv.x*w2.x + hv.y*w2.y + hv.z*w2.z + hv.w*w2.w;
                }
            }
#pragma unroll
            for (int r = 0; r < BT; ++r) { s_g[j1 * 9 + r] = acc1[r]; s_g[j2 * 9 + r] = acc2[r]; }
        }
        __syncthreads();

        // gate combine + state update + store h to g_enc
        {
            const int u = tid & 127, rr = tid >> 7;
#pragma unroll
            for (int q = 0; q < 4; ++q) {
                const int r = rr + q * 2;
                float gi = s_g[u * 9 + r];
                float gf = s_g[(128 + u) * 9 + r];
                float gg = s_g[(256 + u) * 9 + r];
                float go = s_g[(384 + u) * 9 + r];
                float c = sigf(gf) * s_c[r][u] + sigf(gi) * tanhff(gg);
                float h = sigf(go) * tanhff(c);
                s_c[r][u] = c; s_h[r][u] = h;
                g_enc[((size_t)(b0 + r) * LK + t) * HH + u] = h;
            }
        }
        __syncthreads();
    }

    // ================= DECODER: 3 steps =================
    // re-init h_de, c_de = 0 (dec_out == h_de throughout)
    for (int i = tid; i < BT * HH; i += NTHR) { (&s_h[0][0])[i] = 0.0f; (&s_c[0][0])[i] = 0.0f; }
    __syncthreads();

    const int jd   = tid & 127;
    const int half = tid >> 7;

#pragma unroll 1
    for (int step = 0; step < NOUT; ++step) {
        const float* W = ddw + (size_t)step * 256 * 128;

        // hpart[r][j] = dd_b[j] + h_de[r] . W[128: , j]   (t-independent half)
        {
            float a[4];
            const float bv = ddb[step * 128 + jd];
#pragma unroll
            for (int q = 0; q < 4; ++q) a[q] = bv;
            for (int k = 0; k < HH; ++k) {
                float wv = W[(128 + k) * 128 + jd];
#pragma unroll
                for (int q = 0; q < 4; ++q) a[q] += s_h[half * 4 + q][k] * wv;
            }
#pragma unroll
            for (int q = 0; q < 4; ++q) s_hp[half * 4 + q][jd] = a[q];
        }
        __syncthreads();

        // big GEMM: e1[r,t,j] = tanh(hpart[r][j] + enc[r,t,:] . W[:128, j]); score = e1 . dl_w
        const float dl = dlw[step * 128 + jd];
#pragma unroll 1
        for (int g = 0; g < 8; ++g) {
            float acc[25];
            int ebase[25];
#pragma unroll
            for (int p = 0; p < 25; ++p) {
                int rt = (g * 25 + p) * 2 + half;
                int r = rt / 50, tt = rt - r * 50;
                ebase[p] = ((b0 + r) * LK + tt) * HH;
                acc[p] = s_hp[r][jd];
            }
#pragma unroll 1
            for (int kc = 0; kc < HH; kc += 8) {
                float wv[8];
#pragma unroll
                for (int q = 0; q < 8; ++q) wv[q] = W[(kc + q) * 128 + jd];
#pragma unroll
                for (int p = 0; p < 25; ++p) {
                    const float4 e0 = *(const float4*)(g_enc + ebase[p] + kc);
                    const float4 e1 = *(const float4*)(g_enc + ebase[p] + kc + 4);
                    acc[p] += e0.x*wv[0] + e0.y*wv[1] + e0.z*wv[2] + e0.w*wv[3]
                            + e1.x*wv[4] + e1.y*wv[5] + e1.z*wv[6] + e1.w*wv[7];
                }
            }
#pragma unroll
            for (int p = 0; p < 25; ++p) {
                float v = tanhff(acc[p]) * dl;
#pragma unroll
                for (int m = 32; m > 0; m >>= 1) v += __shfl_xor(v, m, 64);
                if ((tid & 63) == 0) {
                    int rt = (g * 25 + p) * 2 + half;
                    s_part[tid >> 6][rt] = v;
                }
            }
        }
        __syncthreads();

        // combine wave partials + softmax over t (8 serial threads)
        if (tid < BT) {
            const int r = tid;
            const float dlbv = dlb[step];
            float mx = -1e30f;
            for (int tt = 0; tt < LK; ++tt) {
                int rt = r * LK + tt;
                int w0 = (rt & 1) * 2;
                float s = s_part[w0][rt] + s_part[w0 + 1][rt] + dlbv;
                s_alpha[r][tt] = s;
                mx = fmaxf(mx, s);
            }
            float sm = 0.0f;
            for (int tt = 0; tt < LK; ++tt) { float e = __expf(s_alpha[r][tt] - mx); sm += e; s_alpha[r][tt] = e; }
            float inv = 1.0f / sm;
            for (int tt = 0; tt < LK; ++tt) s_alpha[r][tt] *= inv;
        }
        __syncthreads();

        // ctx[r][j] = sum_t alpha[r,t] * enc[r,t,j]
        {
            float a[4];
#pragma unroll
            for (int q = 0; q < 4; ++q) a[q] = 0.0f;
            for (int tt = 0; tt < LK; ++tt) {
#pragma unroll
                for (int q = 0; q < 4; ++q) {
                    int r = half * 4 + q;
                    a[q] += s_alpha[r][tt] * g_enc[((size_t)(b0 + r) * LK + tt) * HH + jd];
                }
            }
#pragma unroll
            for (int q = 0; q < 4; ++q) s_ctx[half * 4 + q][jd] = a[q];
        }
        __syncthreads();

        // decoder LSTM: dec_in = [ctx, h_de_prev], K = 256 (Wih) + 128 (Whh)
        {
            const int j1 = tid, j2 = tid + 256;
            float acc1[BT], acc2[BT];
            const float bb1 = dbih[j1] + dbhh[j1];
            const float bb2 = dbih[j2] + dbhh[j2];
#pragma unroll
            for (int r = 0; r < BT; ++r) { acc1[r] = bb1; acc2[r] = bb2; }
            const float4* w1p = (const float4*)(dWih + j1 * 256);
            const float4* w2p = (const float4*)(dWih + j2 * 256);
#pragma unroll 4
            for (int kc = 0; kc < 32; ++kc) {  // k in [0,128): ctx
                float4 w1 = w1p[kc], w2 = w2p[kc];
#pragma unroll
                for (int r = 0; r < BT; ++r) {
                    float4 xv = *(const float4*)&s_ctx[r][kc * 4];
                    acc1[r] += xv.x*w1.x + xv.y*w1.y + xv.z*w1.z + xv.w*w1.w;
                    acc2[r] += xv.x*w2.x + xv.y*w2.y + xv.z*w2.z + xv.w*w2.w;
                }
            }
#pragma unroll 4
            for (int kc = 0; kc < 32; ++kc) {  // k in [128,256): h_de_prev
                float4 w1 = w1p[32 + kc], w2 = w2p[32 + kc];
#pragma unroll
                for (int r = 0; r < BT; ++r) {
                    float4 hv = *(const float4*)&s_h[r][kc * 4];
                    acc1[r] += hv.x*w1.x + hv.y*w1.y + hv.z*w1.z + hv.w*w1.w;
                    acc2[r] += hv.x*w2.x + hv.y*w2.y + hv.z*w2.z + hv.w*w2.w;
                }
            }
            const float4* u1p = (const float4*)(dWhh + j1 * HH);
            const float4* u2p = (const float4*)(dWhh + j2 * HH);
#pragma unroll 4
            for (int kc = 0; kc < 32; ++kc) {  // recurrent term
                float4 w1 = u1p[kc], w2 = u2p[kc];
#pragma unroll
                for (int r = 0; r < BT; ++r) {
                    float4 hv = *(const float4*)&s_h[r][kc * 4];
                    acc1[r] += hv.x*w1.x + hv.y*w1.y + hv.z*w1.z + hv.w*w1.w;
                    acc2[r] += hv.x*w2.x + hv.y*w2.y + hv.z*w2.z + hv.w*w2.w;
                }
            }
#pragma unroll
            for (int r = 0; r < BT; ++r) { s_g[j1 * 9 + r] = acc1[r]; s_g[j2 * 9 + r] = acc2[r]; }
        }
        __syncthreads();

        // gate combine
        {
            const int u = tid & 127, rr = tid >> 7;
#pragma unroll
            for (int q = 0; q < 4; ++q) {
                const int r = rr + q * 2;
                float gi = s_g[u * 9 + r];
                float gf = s_g[(128 + u) * 9 + r];
                float gg = s_g[(256 + u) * 9 + r];
                float go = s_g[(384 + u) * 9 + r];
                float c = sigf(gf) * s_c[r][u] + sigf(gi) * tanhff(gg);
                float h = sigf(go) * tanhff(c);
                s_c[r][u] = c; s_h[r][u] = h;
            }
        }
        __syncthreads();

        // head: y1 = tanh(h_de @ fc_w + fc_b)
        {
            const int f = tid & 63, rh = tid >> 6;
#pragma unroll
            for (int q = 0; q < 2; ++q) {
                const int r = rh + q * 4;
                float a = fcb[step * 64 + f];
#pragma unroll 4
                for (int u = 0; u < HH; ++u) a += s_h[r][u] * fcw[(step * 128 + u) * 64 + f];
                s_y1[r][f] = tanhff(a);
            }
        }
        __syncthreads();

        // out = sigmoid(y1 @ out_w + out_b)
        if (tid < BT) {
            const int r = tid;
            float a = ob[step];
            for (int f = 0; f < FF; ++f) a += s_y1[r][f] * ow[step * 64 + f];
            out[(b0 + r) * NOUT + step] = sigf(a);
        }
        __syncthreads();
    }
}

extern "C" void kernel_launch(void* const* d_in, const int* in_sizes, int n_in,
                              void* d_out, int out_size, void* d_ws, size_t ws_size,
                              hipStream_t stream) {
    const float* x    = (const float*)d_in[0];
    const float* eWih = (const float*)d_in[1];
    const float* eWhh = (const float*)d_in[2];
    const float* ebih = (const float*)d_in[3];
    const float* ebhh = (const float*)d_in[4];
    const float* aw   = (const float*)d_in[5];
    const float* ab   = (const float*)d_in[6];
    const float* dWih = (const float*)d_in[7];
    const float* dWhh = (const float*)d_in[8];
    const float* dbih = (const float*)d_in[9];
    const float* dbhh = (const float*)d_in[10];
    const float* ddw  = (const float*)d_in[11];
    const float* ddb  = (const float*)d_in[12];
    const float* dlw  = (const float*)d_in[13];
    const float* dlb  = (const float*)d_in[14];
    const float* fcw  = (const float*)d_in[15];
    const float* fcb  = (const float*)d_in[16];
    const float* ow   = (const float*)d_in[17];
    const float* ob   = (const float*)d_in[18];
    float* out = (float*)d_out;

    darnn_kernel<<<NWG, NTHR, 0, stream>>>(x, eWih, eWhh, ebih, ebhh, aw, ab,
                                           dWih, dWhh, dbih, dbhh, ddw, ddb,
                                           dlw, dlb, fcw, fcb, ow, ob, out);
}

// Round 2
// 1653.769 us; speedup vs baseline: 1.5935x; 1.5935x over previous
//
#include <hip/hip_runtime.h>
#include <cmath>

#define LK   50      // look_back
#define NOUT 3
#define FF   64      // feature_num
#define BB   2048    // batch
#define HH   128     // units
#define BT   8       // batch rows per workgroup
#define NWG  (BB/BT) // 256 workgroups
#define NTHR 1024    // 16 waves/WG -> 4 waves/SIMD

// encoder outputs [B][L][H] — device global (52.4 MB BSS)
__device__ float g_enc[(size_t)BB * LK * HH];

__device__ __forceinline__ float sigf(float x) { return 1.0f / (1.0f + __expf(-x)); }
__device__ __forceinline__ float tanhff(float x) {
    return 1.0f - 2.0f / (__expf(2.0f * x) + 1.0f);
}

__global__ __launch_bounds__(NTHR)
void darnn_kernel(const float* __restrict__ x,
                  const float* __restrict__ eWih, const float* __restrict__ eWhh,
                  const float* __restrict__ ebih, const float* __restrict__ ebhh,
                  const float* __restrict__ aw,   const float* __restrict__ ab,
                  const float* __restrict__ dWih, const float* __restrict__ dWhh,
                  const float* __restrict__ dbih, const float* __restrict__ dbhh,
                  const float* __restrict__ ddw,  const float* __restrict__ ddb,
                  const float* __restrict__ dlw,  const float* __restrict__ dlb,
                  const float* __restrict__ fcw,  const float* __restrict__ fcb,
                  const float* __restrict__ ow,   const float* __restrict__ ob,
                  float* __restrict__ out)
{
    __shared__ float s_h[BT][HH];        // hidden state
    __shared__ float s_c[BT][HH];        // cell state
    __shared__ float s_xt[BT][FF];       // x tile for step t
    __shared__ float s_ap[2][BT][FF];    // attention K-split partials
    __shared__ float s_eb[BT][FF];       // xin after softmax
    __shared__ float s_g[1024 * 9];      // gate partials: [kh*512+j]*9 + r
    __shared__ float s_hp[BT][HH];       // decoder hpart
    __shared__ float s_part[2][BT * LK]; // per-wave score partials
    __shared__ float s_alpha[BT][LK];    // temporal attention weights
    __shared__ float s_ctx[BT][HH];      // context vector
    __shared__ float s_y1[BT][FF];       // head intermediate

    const int tid = threadIdx.x;
    const int b0  = blockIdx.x * BT;

    // init h, c = 0  (exactly 1024 = 8*128 items)
    (&s_h[0][0])[tid & 1023] = 0.0f;
    (&s_c[0][0])[tid & 1023] = 0.0f;
    __syncthreads();

    // ================= ENCODER: 50 steps =================
#pragma unroll 1
    for (int t = 0; t < LK; ++t) {
        // stage x_t tile (512 items)
        if (tid < BT * FF) {
            int r = tid >> 6, f = tid & 63;
            s_xt[r][f] = x[((b0 + r) * LK + t) * FF + f];
        }
        __syncthreads();

        // input attention, K-split: kh=0 -> xt(64)+h[0:32]; kh=1 -> h[32:128]
        {
            const int kh = tid >> 9, r = (tid >> 6) & 7, col = tid & 63;
            const float* w = aw + (size_t)t * 192 * 64 + col;
            float a;
            if (kh == 0) {
                a = ab[t * FF + col];
#pragma unroll 8
                for (int k = 0; k < FF; ++k) a += s_xt[r][k] * w[k * 64];
#pragma unroll 8
                for (int k = 0; k < 32; ++k) a += s_h[r][k] * w[(64 + k) * 64];
            } else {
                a = 0.0f;
#pragma unroll 8
                for (int k = 32; k < HH; ++k) a += s_h[r][k] * w[(64 + k) * 64];
            }
            s_ap[kh][r][col] = a;
        }
        __syncthreads();

        // softmax over 64 features: wave r handles row r, lane = feature
        if (tid < 512) {
            const int r = tid >> 6, f = tid & 63;
            float e = tanhff(s_ap[0][r][f] + s_ap[1][r][f]);
            float mx = e;
#pragma unroll
            for (int m = 1; m < 64; m <<= 1) mx = fmaxf(mx, __shfl_xor(mx, m, 64));
            float ex = __expf(e - mx);
            float sm = ex;
#pragma unroll
            for (int m = 1; m < 64; m <<= 1) sm += __shfl_xor(sm, m, 64);
            s_eb[r][f] = ex / sm * s_xt[r][f];
        }
        __syncthreads();

        // LSTM gates, K-split: kh=0 -> xin(64)+h[0:32]; kh=1 -> h[32:128]
        {
            const int kh = tid >> 9, j = tid & 511;
            float acc[BT];
            const float bv = (kh == 0) ? (ebih[j] + ebhh[j]) : 0.0f;
#pragma unroll
            for (int r = 0; r < BT; ++r) acc[r] = bv;
            if (kh == 0) {
                const float4* wp = (const float4*)(eWih + j * FF);
#pragma unroll 4
                for (int kc = 0; kc < 16; ++kc) {
                    float4 w4 = wp[kc];
#pragma unroll
                    for (int r = 0; r < BT; ++r) {
                        float4 xv = *(const float4*)&s_eb[r][kc * 4];
                        acc[r] += xv.x*w4.x + xv.y*w4.y + xv.z*w4.z + xv.w*w4.w;
                    }
                }
                const float4* up = (const float4*)(eWhh + j * HH);
#pragma unroll 4
                for (int kc = 0; kc < 8; ++kc) {
                    float4 w4 = up[kc];
#pragma unroll
                    for (int r = 0; r < BT; ++r) {
                        float4 hv = *(const float4*)&s_h[r][kc * 4];
                        acc[r] += hv.x*w4.x + hv.y*w4.y + hv.z*w4.z + hv.w*w4.w;
                    }
                }
            } else {
                const float4* up = (const float4*)(eWhh + j * HH);
#pragma unroll 4
                for (int kc = 8; kc < 32; ++kc) {
                    float4 w4 = up[kc];
#pragma unroll
                    for (int r = 0; r < BT; ++r) {
                        float4 hv = *(const float4*)&s_h[r][kc * 4];
                        acc[r] += hv.x*w4.x + hv.y*w4.y + hv.z*w4.z + hv.w*w4.w;
                    }
                }
            }
            const int base = (kh * 512 + j) * 9;
#pragma unroll
            for (int r = 0; r < BT; ++r) s_g[base + r] = acc[r];
        }
        __syncthreads();

        // gate combine + state update + store h (1024 = 8r x 128u items)
        {
            const int u = tid & 127, r = tid >> 7;
            float gi = s_g[u * 9 + r]         + s_g[(512 + u) * 9 + r];
            float gf = s_g[(128 + u) * 9 + r] + s_g[(512 + 128 + u) * 9 + r];
            float gg = s_g[(256 + u) * 9 + r] + s_g[(512 + 256 + u) * 9 + r];
            float go = s_g[(384 + u) * 9 + r] + s_g[(512 + 384 + u) * 9 + r];
            float c = sigf(gf) * s_c[r][u] + sigf(gi) * tanhff(gg);
            float h = sigf(go) * tanhff(c);
            s_c[r][u] = c; s_h[r][u] = h;
            g_enc[((size_t)(b0 + r) * LK + t) * HH + u] = h;
        }
        __syncthreads();
    }

    // ================= DECODER: 3 steps =================
    (&s_h[0][0])[tid & 1023] = 0.0f;
    (&s_c[0][0])[tid & 1023] = 0.0f;
    __syncthreads();

#pragma unroll 1
    for (int step = 0; step < NOUT; ++step) {
        const float* W = ddw + (size_t)step * 256 * 128;

        // hpart[r][j] = dd_b[j] + h_de[r] . W[128:, j]   (1024 items, K=128)
        {
            const int jd = tid & 127, r = tid >> 7;
            float a = ddb[step * 128 + jd];
#pragma unroll 8
            for (int k = 0; k < HH; ++k) a += s_h[r][k] * W[(128 + k) * 128 + jd];
            s_hp[r][jd] = a;
        }
        __syncthreads();

        // score GEMM: 8 groups of 128 threads; group g2 owns row r=g2, all 50 t
        {
            const int g2 = tid >> 7, jd = tid & 127, wig = (tid >> 6) & 1;
            const float dl = dlw[step * 128 + jd];
            const float hpv = s_hp[g2][jd];
            const float* encrow = g_enc + (size_t)(b0 + g2) * LK * HH;
#pragma unroll 1
            for (int chunk = 0; chunk < 2; ++chunk) {
                float acc[25];
#pragma unroll
                for (int p = 0; p < 25; ++p) acc[p] = hpv;
#pragma unroll 1
                for (int kc = 0; kc < 16; ++kc) {
                    float wv[8];
#pragma unroll
                    for (int q = 0; q < 8; ++q) wv[q] = W[(kc * 8 + q) * 128 + jd];
                    const float* ep = encrow + (chunk * 25) * HH + kc * 8;
#pragma unroll
                    for (int p = 0; p < 25; ++p) {
                        const float4 e0 = *(const float4*)(ep + p * HH);
                        const float4 e1 = *(const float4*)(ep + p * HH + 4);
                        acc[p] += e0.x*wv[0] + e0.y*wv[1] + e0.z*wv[2] + e0.w*wv[3]
                                + e1.x*wv[4] + e1.y*wv[5] + e1.z*wv[6] + e1.w*wv[7];
                    }
                }
#pragma unroll
                for (int p = 0; p < 25; ++p) {
                    float v = tanhff(acc[p]) * dl;
#pragma unroll
                    for (int m = 32; m > 0; m >>= 1) v += __shfl_xor(v, m, 64);
                    if ((tid & 63) == 0) s_part[wig][g2 * LK + chunk * 25 + p] = v;
                }
            }
        }
        __syncthreads();

        // softmax over t: wave r handles row r, lanes 0..49 = t
        if (tid < 512) {
            const int r = tid >> 6, lane = tid & 63;
            float s = (lane < LK)
                ? (s_part[0][r * LK + lane] + s_part[1][r * LK + lane] + dlb[step])
                : -1e30f;
            float mx = s;
#pragma unroll
            for (int m = 1; m < 64; m <<= 1) mx = fmaxf(mx, __shfl_xor(mx, m, 64));
            float ex = (lane < LK) ? __expf(s - mx) : 0.0f;
            float sm = ex;
#pragma unroll
            for (int m = 1; m < 64; m <<= 1) sm += __shfl_xor(sm, m, 64);
            if (lane < LK) s_alpha[r][lane] = ex / sm;
        }
        __syncthreads();

        // ctx[r][jd] = sum_t alpha[r][t] * enc[r][t][jd]   (1024 items, 50 MACs)
        {
            const int jd = tid & 127, r = tid >> 7;
            const float* ep = g_enc + (size_t)(b0 + r) * LK * HH + jd;
            float a = 0.0f;
#pragma unroll 5
            for (int tt = 0; tt < LK; ++tt) a += s_alpha[r][tt] * ep[tt * HH];
            s_ctx[r][jd] = a;
        }
        __syncthreads();

        // decoder LSTM gates, K-split over 384:
        // kh=0: Wih k0..191 (ctx 128 + h 0..63); kh=1: Wih k192..255 (h 64..127) + Whh 128
        {
            const int kh = tid >> 9, j = tid & 511;
            float acc[BT];
            const float bv = (kh == 0) ? (dbih[j] + dbhh[j]) : 0.0f;
#pragma unroll
            for (int r = 0; r < BT; ++r) acc[r] = bv;
            const float4* wp = (const float4*)(dWih + j * 256);
            if (kh == 0) {
#pragma unroll 4
                for (int kc = 0; kc < 32; ++kc) {
                    float4 w4 = wp[kc];
#pragma unroll
                    for (int r = 0; r < BT; ++r) {
                        float4 xv = *(const float4*)&s_ctx[r][kc * 4];
                        acc[r] += xv.x*w4.x + xv.y*w4.y + xv.z*w4.z + xv.w*w4.w;
                    }
                }
#pragma unroll 4
                for (int kc = 32; kc < 48; ++kc) {
                    float4 w4 = wp[kc];
#pragma unroll
                    for (int r = 0; r < BT; ++r) {
                        float4 hv = *(const float4*)&s_h[r][(kc - 32) * 4];
                        acc[r] += hv.x*w4.x + hv.y*w4.y + hv.z*w4.z + hv.w*w4.w;
                    }
                }
            } else {
#pragma unroll 4
                for (int kc = 48; kc < 64; ++kc) {
                    float4 w4 = wp[kc];
#pragma unroll
                    for (int r = 0; r < BT; ++r) {
                        float4 hv = *(const float4*)&s_h[r][(kc - 48 + 16) * 4];
                        acc[r] += hv.x*w4.x + hv.y*w4.y + hv.z*w4.z + hv.w*w4.w;
                    }
                }
                const float4* up = (const float4*)(dWhh + j * HH);
#pragma unroll 4
                for (int kc = 0; kc < 32; ++kc) {
                    float4 w4 = up[kc];
#pragma unroll
                    for (int r = 0; r < BT; ++r) {
                        float4 hv = *(const float4*)&s_h[r][kc * 4];
                        acc[r] += hv.x*w4.x + hv.y*w4.y + hv.z*w4.z + hv.w*w4.w;
                    }
                }
            }
            const int base = (kh * 512 + j) * 9;
#pragma unroll
            for (int r = 0; r < BT; ++r) s_g[base + r] = acc[r];
        }
        __syncthreads();

        // gate combine + state update
        {
            const int u = tid & 127, r = tid >> 7;
            float gi = s_g[u * 9 + r]         + s_g[(512 + u) * 9 + r];
            float gf = s_g[(128 + u) * 9 + r] + s_g[(512 + 128 + u) * 9 + r];
            float gg = s_g[(256 + u) * 9 + r] + s_g[(512 + 256 + u) * 9 + r];
            float go = s_g[(384 + u) * 9 + r] + s_g[(512 + 384 + u) * 9 + r];
            float c = sigf(gf) * s_c[r][u] + sigf(gi) * tanhff(gg);
            float h = sigf(go) * tanhff(c);
            s_c[r][u] = c; s_h[r][u] = h;
        }
        __syncthreads();

        // head: y1 = tanh(h_de @ fc_w + fc_b)  (512 items, K=128)
        if (tid < 512) {
            const int r = tid >> 6, f = tid & 63;
            float a = fcb[step * 64 + f];
#pragma unroll 8
            for (int u = 0; u < HH; ++u) a += s_h[r][u] * fcw[(step * 128 + u) * 64 + f];
            s_y1[r][f] = tanhff(a);
        }
        __syncthreads();

        // out = sigmoid(y1 @ out_w + out_b)
        if (tid < BT) {
            const int r = tid;
            float a = ob[step];
            for (int f = 0; f < FF; ++f) a += s_y1[r][f] * ow[step * 64 + f];
            out[(b0 + r) * NOUT + step] = sigf(a);
        }
        __syncthreads();
    }
}

extern "C" void kernel_launch(void* const* d_in, const int* in_sizes, int n_in,
                              void* d_out, int out_size, void* d_ws, size_t ws_size,
                              hipStream_t stream) {
    const float* x    = (const float*)d_in[0];
    const float* eWih = (const float*)d_in[1];
    const float* eWhh = (const float*)d_in[2];
    const float* ebih = (const float*)d_in[3];
    const float* ebhh = (const float*)d_in[4];
    const float* aw   = (const float*)d_in[5];
    const float* ab   = (const float*)d_in[6];
    const float* dWih = (const float*)d_in[7];
    const float* dWhh = (const float*)d_in[8];
    const float* dbih = (const float*)d_in[9];
    const float* dbhh = (const float*)d_in[10];
    const float* ddw  = (const float*)d_in[11];
    const float* ddb  = (const float*)d_in[12];
    const float* dlw  = (const float*)d_in[13];
    const float* dlb  = (const float*)d_in[14];
    const float* fcw  = (const float*)d_in[15];
    const float* fcb  = (const float*)d_in[16];
    const float* ow   = (const float*)d_in[17];
    const float* ob   = (const float*)d_in[18];
    float* out = (float*)d_out;

    darnn_kernel<<<NWG, NTHR, 0, stream>>>(x, eWih, eWhh, ebih, ebhh, aw, ab,
                                           dWih, dWhh, dbih, dbhh, ddw, ddb,
                                           dlw, dlb, fcw, fcb, ow, ob, out);
}

// Round 3
// 613.921 us; speedup vs baseline: 4.2927x; 2.6938x over previous
//
#include <hip/hip_runtime.h>

#define LK   50      // look_back
#define NOUT 3
#define FF   64      // feature_num
#define BB   2048    // batch
#define HH   128     // units
#define BT   8       // batch rows per workgroup
#define NWG  (BB/BT) // 256 workgroups
#define NTHR 1024    // 16 waves

typedef unsigned short u16;
typedef unsigned int   u32;
typedef __attribute__((ext_vector_type(8))) short short8;
typedef __attribute__((ext_vector_type(4))) float f32x4;

#define MFMA16(a,b,c) __builtin_amdgcn_mfma_f32_16x16x32_bf16(a,b,c,0,0,0)

// pre-converted bf16 buffers (device globals; rewritten every launch)
__device__ u16 g_xbf [(size_t)BB*LK*FF];   // x,            [b][t][f]
__device__ u16 g_awT [(size_t)LK*64*192];  // attn_w^T,     [t][c][k]   k:[xt(64)|h(128)]
__device__ u16 g_eW  [512*192];            // enc LSTM,     [gate][k]   k:[xin(64)|h(128)]
__device__ u16 g_dW  [512*384];            // dec LSTM,     [gate][k]   k:[ctx(128)|h(128)|h(128)]
__device__ u16 g_ddwT[NOUT*128*256];       // dd_w^T,       [s][n][k]   k:[enc(128)|h(128)]
__device__ u16 g_fcwT[NOUT*64*128];        // fc_w^T,       [s][n][k]
__device__ u16 g_encbf[(size_t)BB*LK*HH];  // encoder outputs bf16

__device__ __forceinline__ float sigf(float x) { return 1.0f / (1.0f + __expf(-x)); }
__device__ __forceinline__ float tanhff(float x) { return 1.0f - 2.0f / (__expf(2.0f * x) + 1.0f); }
__device__ __forceinline__ u16 f2b(float f) {
    union { float f; u32 u; } v; v.f = f;
    u32 r = v.u + 0x7fffu + ((v.u >> 16) & 1u);
    return (u16)(r >> 16);
}
__device__ __forceinline__ float b2f(u16 h) {
    union { u32 u; float f; } v; v.u = ((u32)h) << 16; return v.f;
}

__global__ __launch_bounds__(256)
void convert_kernel(const float* __restrict__ x,
                    const float* __restrict__ eWih, const float* __restrict__ eWhh,
                    const float* __restrict__ aw,
                    const float* __restrict__ dWih, const float* __restrict__ dWhh,
                    const float* __restrict__ ddw,  const float* __restrict__ fcw)
{
    const int gid = blockIdx.x * blockDim.x + threadIdx.x;
    const int stride = gridDim.x * blockDim.x;
    for (int i = gid; i < BB*LK*FF; i += stride) g_xbf[i] = f2b(x[i]);
    for (int i = gid; i < LK*64*192; i += stride) {
        int t = i / 12288, rm = i % 12288, c = rm / 192, k = rm % 192;
        g_awT[i] = f2b(aw[((size_t)t*192 + k)*64 + c]);
    }
    for (int i = gid; i < 512*192; i += stride) {
        int j = i / 192, k = i % 192;
        g_eW[i] = f2b(k < 64 ? eWih[j*64 + k] : eWhh[j*128 + (k-64)]);
    }
    for (int i = gid; i < 512*384; i += stride) {
        int j = i / 384, k = i % 384;
        g_dW[i] = f2b(k < 256 ? dWih[j*256 + k] : dWhh[j*128 + (k-256)]);
    }
    for (int i = gid; i < NOUT*128*256; i += stride) {
        int s = i / 32768, rm = i % 32768, n = rm / 256, k = rm % 256;
        g_ddwT[i] = f2b(ddw[((size_t)s*256 + k)*128 + n]);
    }
    for (int i = gid; i < NOUT*64*128; i += stride) {
        int s = i / 8192, rm = i % 8192, n = rm / 128, k = rm % 128;
        g_fcwT[i] = f2b(fcw[((size_t)s*128 + k)*64 + n]);
    }
}

__global__ __launch_bounds__(NTHR)
void darnn_kernel(const float* __restrict__ ab,
                  const float* __restrict__ ebih, const float* __restrict__ ebhh,
                  const float* __restrict__ dbih, const float* __restrict__ dbhh,
                  const float* __restrict__ ddb,
                  const float* __restrict__ dlw,  const float* __restrict__ dlb,
                  const float* __restrict__ fcb,
                  const float* __restrict__ ow,   const float* __restrict__ ob,
                  float* __restrict__ out)
{
    // A-tiles: bf16, M=16 rows (8 used, rows 8..15 stay zero), K contiguous, pitch padded
    __shared__ u16  s_Ax [16][200];  // [xt(0:64) | h(64:192)]
    __shared__ u16  s_Ain[16][200];  // [xin(0:64)| h(64:192)]
    __shared__ u16  s_Adec[16][392]; // [ctx(0:128)| h(128:256)| h(256:384)]
    __shared__ float s_e[8][64];     // attn pre-tanh scores
    __shared__ float s_g[512*9];     // gate pre-activations, pitch 9
    __shared__ float s_c[8][128];    // cell state fp32
    __shared__ float s_hp[8][128];   // decoder hpart
    __shared__ float s_spart[4][400];// score partials per nt-pair
    __shared__ float s_alpha[8][LK]; // temporal attn weights
    __shared__ float s_y1[8][64];    // head intermediate
    __shared__ float s_ebias[512];
    __shared__ float s_dbias[512];

    const int tid  = threadIdx.x;
    const int b0   = blockIdx.x * BT;
    const int wv   = tid >> 6;
    const int lane = tid & 63;
    const int quad = lane >> 4;
    const int l16  = lane & 15;

    // init: zero A-tiles (rows 8..15 must stay zero forever), cell state, bias sums
    for (int i = tid; i < 16*200; i += NTHR) { (&s_Ax[0][0])[i] = 0; (&s_Ain[0][0])[i] = 0; }
    for (int i = tid; i < 16*392; i += NTHR) (&s_Adec[0][0])[i] = 0;
    (&s_c[0][0])[tid] = 0.0f;
    if (tid < 512) { s_ebias[tid] = ebih[tid] + ebhh[tid]; s_dbias[tid] = dbih[tid] + dbhh[tid]; }
    __syncthreads();

    // ================= ENCODER =================
#pragma unroll 1
    for (int t = 0; t < LK; ++t) {
        // E1: stage x_t (bf16)
        if (tid < 512) {
            int r = tid >> 6, f = tid & 63;
            s_Ax[r][f] = g_xbf[((size_t)(b0 + r) * LK + t) * FF + f];
        }
        __syncthreads();

        // E2: attention GEMM [16,192]x[192,64] — 4 waves, one 16-col tile each
        if (wv < 4) {
            f32x4 acc = {0.f, 0.f, 0.f, 0.f};
            const int f = wv * 16 + l16;
            const u16* bp = g_awT + (size_t)t * 64 * 192 + f * 192 + quad * 8;
#pragma unroll
            for (int ks = 0; ks < 6; ++ks) {
                short8 av = *(const short8*)&s_Ax[l16][ks * 32 + quad * 8];
                short8 bv = *(const short8*)(bp + ks * 32);
                acc = MFMA16(av, bv, acc);
            }
            float abv = ab[t * FF + f];
            if (quad < 2) {
#pragma unroll
                for (int rg = 0; rg < 4; ++rg) s_e[quad * 4 + rg][f] = acc[rg] + abv;
            }
        }
        __syncthreads();

        // E3: softmax over 64 features; xin = softmax(tanh(e)) * xt
        if (tid < 512) {
            const int r = tid >> 6;
            float e = tanhff(s_e[r][lane]);
            float mx = e;
#pragma unroll
            for (int m = 1; m < 64; m <<= 1) mx = fmaxf(mx, __shfl_xor(mx, m, 64));
            float ex = __expf(e - mx);
            float sm = ex;
#pragma unroll
            for (int m = 1; m < 64; m <<= 1) sm += __shfl_xor(sm, m, 64);
            s_Ain[r][lane] = f2b(ex / sm * b2f(s_Ax[r][lane]));
        }
        __syncthreads();

        // E4: LSTM gate GEMM [16,192]x[192,512] — 16 waves x 2 col-tiles x 6 K
        {
            const int n0 = wv * 32;
            f32x4 a0 = {0.f,0.f,0.f,0.f}, a1 = {0.f,0.f,0.f,0.f};
            const u16* bp0 = g_eW + (n0 + l16) * 192 + quad * 8;
            const u16* bp1 = bp0 + 16 * 192;
#pragma unroll
            for (int ks = 0; ks < 6; ++ks) {
                short8 av = *(const short8*)&s_Ain[l16][ks * 32 + quad * 8];
                a0 = MFMA16(av, *(const short8*)(bp0 + ks * 32), a0);
                a1 = MFMA16(av, *(const short8*)(bp1 + ks * 32), a1);
            }
            if (quad < 2) {
#pragma unroll
                for (int rg = 0; rg < 4; ++rg) {
                    int r = quad * 4 + rg;
                    s_g[(n0 + l16) * 9 + r]      = a0[rg];
                    s_g[(n0 + 16 + l16) * 9 + r] = a1[rg];
                }
            }
        }
        __syncthreads();

        // E5: gate combine + state update + enc store
        {
            const int u = tid & 127, r = tid >> 7;
            float gi = s_g[u * 9 + r]         + s_ebias[u];
            float gf = s_g[(128 + u) * 9 + r] + s_ebias[128 + u];
            float gg = s_g[(256 + u) * 9 + r] + s_ebias[256 + u];
            float go = s_g[(384 + u) * 9 + r] + s_ebias[384 + u];
            float c = sigf(gf) * s_c[r][u] + sigf(gi) * tanhff(gg);
            float h = sigf(go) * tanhff(c);
            s_c[r][u] = c;
            u16 hb = f2b(h);
            s_Ax[r][64 + u] = hb;
            s_Ain[r][64 + u] = hb;
            g_encbf[((size_t)(b0 + r) * LK + t) * HH + u] = hb;
        }
        __syncthreads();
    }

    // ================= DECODER =================
    (&s_c[0][0])[tid] = 0.0f;   // h region of s_Adec is still zero from init
    __syncthreads();

#pragma unroll 1
    for (int s = 0; s < NOUT; ++s) {
        // D1: hpart = h_de @ ddw[128:,:] + ddb   (8 waves, one 16-col tile each)
        if (wv < 8) {
            const int n = wv * 16 + l16;
            f32x4 acc = {0.f,0.f,0.f,0.f};
            const u16* bp = g_ddwT + s * 32768 + n * 256 + 128 + quad * 8;
#pragma unroll
            for (int ks = 0; ks < 4; ++ks) {
                short8 av = *(const short8*)&s_Adec[l16][128 + ks * 32 + quad * 8];
                acc = MFMA16(av, *(const short8*)(bp + ks * 32), acc);
            }
            float db = ddb[s * 128 + n];
            if (quad < 2) {
#pragma unroll
                for (int rg = 0; rg < 4; ++rg) s_hp[quad * 4 + rg][n] = acc[rg] + db;
            }
        }
        __syncthreads();

        // D2: score GEMM [400,128]x[128,128] + tanh + dl_w reduce
        {
            const int np = wv & 3, mq = wv >> 2, n0 = np * 32;
            short8 bfr[8];
            const u16* bp = g_ddwT + s * 32768 + (n0 + l16) * 256 + quad * 8;
#pragma unroll
            for (int nn = 0; nn < 2; ++nn)
#pragma unroll
                for (int ks = 0; ks < 4; ++ks)
                    bfr[nn * 4 + ks] = *(const short8*)(bp + nn * 4096 + ks * 32);
            const float dl0 = dlw[s * 128 + n0 + l16];
            const float dl1 = dlw[s * 128 + n0 + 16 + l16];
#pragma unroll 1
            for (int mt = mq; mt < 25; mt += 4) {
                f32x4 a0 = {0.f,0.f,0.f,0.f}, a1 = {0.f,0.f,0.f,0.f};
                const u16* ap = g_encbf + ((size_t)b0 * LK + mt * 16 + l16) * HH + quad * 8;
#pragma unroll
                for (int ks = 0; ks < 4; ++ks) {
                    short8 av = *(const short8*)(ap + ks * 32);
                    a0 = MFMA16(av, bfr[ks], a0);
                    a1 = MFMA16(av, bfr[4 + ks], a1);
                }
#pragma unroll
                for (int rg = 0; rg < 4; ++rg) {
                    int rt = mt * 16 + quad * 4 + rg;
                    int r  = rt / LK;
                    float v = tanhff(a0[rg] + s_hp[r][n0 + l16]) * dl0
                            + tanhff(a1[rg] + s_hp[r][n0 + 16 + l16]) * dl1;
                    v += __shfl_xor(v, 1, 64); v += __shfl_xor(v, 2, 64);
                    v += __shfl_xor(v, 4, 64); v += __shfl_xor(v, 8, 64);
                    if (l16 == 0) s_spart[np][rt] = v;
                }
            }
        }
        __syncthreads();

        // D3: softmax over t (wave per row)
        if (tid < 512) {
            const int r = tid >> 6;
            float sv = (lane < LK)
                ? (s_spart[0][r * LK + lane] + s_spart[1][r * LK + lane] +
                   s_spart[2][r * LK + lane] + s_spart[3][r * LK + lane] + dlb[s])
                : -1e30f;
            float mx = sv;
#pragma unroll
            for (int m = 1; m < 64; m <<= 1) mx = fmaxf(mx, __shfl_xor(mx, m, 64));
            float ex = (lane < LK) ? __expf(sv - mx) : 0.0f;
            float sm = ex;
#pragma unroll
            for (int m = 1; m < 64; m <<= 1) sm += __shfl_xor(sm, m, 64);
            if (lane < LK) s_alpha[r][lane] = ex / sm;
        }
        __syncthreads();

        // D4: ctx = sum_t alpha * enc  (1024 threads)
        {
            const int jd = tid & 127, r = tid >> 7;
            const u16* ep = g_encbf + (size_t)(b0 + r) * LK * HH + jd;
            float a = 0.0f;
#pragma unroll 10
            for (int tt = 0; tt < LK; ++tt) a += s_alpha[r][tt] * b2f(ep[tt * HH]);
            s_Adec[r][jd] = f2b(a);
        }
        __syncthreads();

        // D5: decoder LSTM gates [16,384]x[384,512]
        {
            const int n0 = wv * 32;
            f32x4 a0 = {0.f,0.f,0.f,0.f}, a1 = {0.f,0.f,0.f,0.f};
            const u16* bp0 = g_dW + (n0 + l16) * 384 + quad * 8;
            const u16* bp1 = bp0 + 16 * 384;
#pragma unroll
            for (int ks = 0; ks < 12; ++ks) {
                short8 av = *(const short8*)&s_Adec[l16][ks * 32 + quad * 8];
                a0 = MFMA16(av, *(const short8*)(bp0 + ks * 32), a0);
                a1 = MFMA16(av, *(const short8*)(bp1 + ks * 32), a1);
            }
            if (quad < 2) {
#pragma unroll
                for (int rg = 0; rg < 4; ++rg) {
                    int r = quad * 4 + rg;
                    s_g[(n0 + l16) * 9 + r]      = a0[rg];
                    s_g[(n0 + 16 + l16) * 9 + r] = a1[rg];
                }
            }
        }
        __syncthreads();

        // D6: gate combine + state update
        {
            const int u = tid & 127, r = tid >> 7;
            float gi = s_g[u * 9 + r]         + s_dbias[u];
            float gf = s_g[(128 + u) * 9 + r] + s_dbias[128 + u];
            float gg = s_g[(256 + u) * 9 + r] + s_dbias[256 + u];
            float go = s_g[(384 + u) * 9 + r] + s_dbias[384 + u];
            float c = sigf(gf) * s_c[r][u] + sigf(gi) * tanhff(gg);
            float h = sigf(go) * tanhff(c);
            s_c[r][u] = c;
            u16 hb = f2b(h);
            s_Adec[r][128 + u] = hb;
            s_Adec[r][256 + u] = hb;
        }
        __syncthreads();

        // D7: head y1 = tanh(h @ fc_w + fc_b)  (4 waves)
        if (wv < 4) {
            const int n = wv * 16 + l16;
            f32x4 acc = {0.f,0.f,0.f,0.f};
            const u16* bp = g_fcwT + s * 8192 + n * 128 + quad * 8;
#pragma unroll
            for (int ks = 0; ks < 4; ++ks) {
                short8 av = *(const short8*)&s_Adec[l16][128 + ks * 32 + quad * 8];
                acc = MFMA16(av, *(const short8*)(bp + ks * 32), acc);
            }
            float fb = fcb[s * 64 + n];
            if (quad < 2) {
#pragma unroll
                for (int rg = 0; rg < 4; ++rg) s_y1[quad * 4 + rg][n] = tanhff(acc[rg] + fb);
            }
        }
        __syncthreads();

        // D8: out = sigmoid(y1 @ out_w + out_b)
        if (tid < 512) {
            const int r = tid >> 6;
            float v = s_y1[r][lane] * ow[s * 64 + lane];
#pragma unroll
            for (int m = 1; m < 64; m <<= 1) v += __shfl_xor(v, m, 64);
            if (lane == 0) out[(b0 + r) * NOUT + s] = sigf(v + ob[s]);
        }
        __syncthreads();
    }
}

extern "C" void kernel_launch(void* const* d_in, const int* in_sizes, int n_in,
                              void* d_out, int out_size, void* d_ws, size_t ws_size,
                              hipStream_t stream) {
    const float* x    = (const float*)d_in[0];
    const float* eWih = (const float*)d_in[1];
    const float* eWhh = (const float*)d_in[2];
    const float* ebih = (const float*)d_in[3];
    const float* ebhh = (const float*)d_in[4];
    const float* aw   = (const float*)d_in[5];
    const float* ab   = (const float*)d_in[6];
    const float* dWih = (const float*)d_in[7];
    const float* dWhh = (const float*)d_in[8];
    const float* dbih = (const float*)d_in[9];
    const float* dbhh = (const float*)d_in[10];
    const float* ddw  = (const float*)d_in[11];
    const float* ddb  = (const float*)d_in[12];
    const float* dlw  = (const float*)d_in[13];
    const float* dlb  = (const float*)d_in[14];
    const float* fcw  = (const float*)d_in[15];
    const float* fcb  = (const float*)d_in[16];
    const float* ow   = (const float*)d_in[17];
    const float* ob   = (const float*)d_in[18];
    float* out = (float*)d_out;

    convert_kernel<<<4096, 256, 0, stream>>>(x, eWih, eWhh, aw, dWih, dWhh, ddw, fcw);
    darnn_kernel<<<NWG, NTHR, 0, stream>>>(ab, ebih, ebhh, dbih, dbhh, ddb,
                                           dlw, dlb, fcb, ow, ob, out);
}